// Round 11
// baseline (197.772 us; speedup 1.0000x reference)
//
#include <hip/hip_runtime.h>
#include <hip/hip_bf16.h>
#include <stdint.h>

// Flash-attention (causal, GQA) B=4, S=1024, HQ=32, HK=8, D=128, fp32 io.
// R4-R9: 32x32x16 MFMAs, S^T orientation, kappa-permuted K (P exits softmax
// in PV A-layout), XCD grouping (bx&7=hk), bf16 prep-pass images +
// global_load_lds DMA dbuf, frag-ordered K image (conflicts == 0).
// R10-R12: launch_bounds 2nd arg = min BLOCKS/CU here; (512,*) experiments
//   showed 2x waves buys nothing -> stall is the per-step convoy.
// R13 (73.5us): static-normalizer softmax (m=8 const, exact rare fallback)
//   -- removing the whole softmax serial chain bought only 2%. Conclusion:
//   per-step wall ~4900 cyc vs ~1500 issued work, invariant to compute/
//   conflicts/waves = the stage->vmcnt(0)->barrier drain itself (m233).
// R14 (compile-fixed R15): attack the drain.
//   (a) L2-thrash fix: Q reads (64MB) + O writes (64MB) stream through the
//       4MB per-XCD L2s and evict the ~2MB K/V workspace working set ->
//       DMA round-trips to L3 (~600cy) every step. Q/O are strictly
//       read/write-once => nontemporal load/store keeps them out of L2;
//       workspace stays L2-resident (~200cy). NOTE: the builtin requires
//       NATIVE vector types -- ext_vector float4 (v4f), not HIP float4.
//   (b) T4 counted vmcnt: each wave issues 4 K-chunks + 4 V-chunks; step =
//       {vmcnt(4) [K landed, V flying] -> bar -> dmaK(t+1) -> QK^T ->
//        vmcnt(4) [V landed, K(t+1) STAYS IN FLIGHT across bar] -> bar ->
//        dmaV(t+1) -> PV}. Loads never drain to 0 in steady state; V wait
//        is covered by QK+softmax compute.
//
// Layout facts (m74/m101-verified): 32x32 C/D: col=lane&31,
// row=(reg&3)+8*(reg>>2)+4*(lane>>5). A: m=lane&31, k=(lane>>5)*8+j.
// B: n=lane&31, k=(lane>>5)*8+j.
// kappa: key kk (0..31) sits at slot mu = (kk&3)+4*((kk>>3)&1)
// +8*(2*((kk>>4)&1)+((kk>>2)&1)) => P regs [8cp..8cp+7] are PV A-frags.

typedef __bf16 v8bf __attribute__((ext_vector_type(8)));
typedef __bf16 v4bf __attribute__((ext_vector_type(4)));
typedef float  v16f __attribute__((ext_vector_type(16)));
typedef float  v4f  __attribute__((ext_vector_type(4)));

#define NB  4
#define NS  1024
#define NHQ 32
#define NHK 8
#define ND  128
#define BQ  128
#define BK  64

#define KOFF(r) (16*((r)>>3) + ((((r)>>2)&1)*4) + ((r)&3))

__device__ __forceinline__ float fexp2(float x) {
  float r; asm("v_exp_f32 %0, %1" : "=v"(r) : "v"(x)); return r;
}
__device__ __forceinline__ float flog2(float x) {
  float r; asm("v_log_f32 %0, %1" : "=v"(r) : "v"(x)); return r;
}

// ---------------- pre-pass: fp32 K/V -> bf16 tile images (R9 layout) ------
// Per (b,hk,t) tile (t = 64-key tile), 32 KB at tileid<<15:
//  K image [0,16K): 16 regions f=(c*8+dM) of 1 KB:
//    byte = f*1024 + half*512 + mu*16 + j*2  (d = dM*16+half*8+j, mu=kappa)
//  V image [16K,32K): byte = d*128 + (g^((d>>1)&7))*16, granule g = 8 keys.
__global__ __launch_bounds__(256)
void prep(const float* __restrict__ kg, const float* __restrict__ vg,
          char* __restrict__ ws)
{
  const int tid = threadIdx.x;
  const int blk = blockIdx.x;
  if (blk < 4096) {                 // ---- K: 1M threads, float4 -> 8B write
    int gid = blk * 256 + tid;
    int i  = gid & 31;              // d-quad, d = 4i..4i+3
    int s  = (gid >> 5) & (NS - 1); // key within (b,hk)
    int hk = (gid >> 15) & 7;
    int b  = gid >> 18;
    v4f f = __builtin_nontemporal_load(
        (const v4f*)(kg + ((size_t)((b * NS + s) * NHK + hk)) * ND + 4 * i));
    v4bf kb;
    kb[0]=(__bf16)f[0]; kb[1]=(__bf16)f[1]; kb[2]=(__bf16)f[2]; kb[3]=(__bf16)f[3];
    int t  = s >> 6;
    int c  = (s >> 5) & 1;
    int kk = s & 31;
    int mu = (kk & 3) + 4 * ((kk >> 3) & 1)
           + 8 * (2 * ((kk >> 4) & 1) + ((kk >> 2) & 1));
    int fidx  = c * 8 + (i >> 2);        // dM = i>>2
    int halfb = (i >> 1) & 1;
    int byte  = fidx * 1024 + halfb * 512 + mu * 16 + ((4 * i) & 7) * 2;
    size_t tb = (size_t)((b * 8 + hk) * 16 + t) << 15;
    *(v4bf*)(ws + tb + byte) = kb;
  } else {                          // ---- V: 0.5M threads, 8 gathers -> 16B
    int vid = (blk - 4096) * 256 + tid;
    int d  = vid & 127;
    int g  = (vid >> 7) & 7;        // granule = 8 keys
    int t  = (vid >> 10) & 15;
    int hk = (vid >> 14) & 7;
    int b  = vid >> 17;
    const float* vp = vg + ((size_t)((b * NS + t * 64 + g * 8) * NHK + hk)) * ND + d;
    v8bf w;
    #pragma unroll
    for (int e = 0; e < 8; ++e)
      w[e] = (__bf16)__builtin_nontemporal_load(vp + (size_t)e * (NHK * ND));
    int byte = (d * 8 + (g ^ ((d >> 1) & 7))) * 16;
    size_t tb = (size_t)((b * 8 + hk) * 16 + t) << 15;
    *(v8bf*)(ws + tb + 16384 + byte) = w;
  }
}

// ---------------- main kernel --------------------------------------------
__global__ __launch_bounds__(256, 2)
void fattn(const float* __restrict__ qg, const char* __restrict__ kvg,
           float* __restrict__ og)
{
  __shared__ __align__(16) char  KV[2][32768];  // [K 16K | V 16K] x dbuf
  __shared__ __align__(16) float alq[4 * 32];   // per-wave alpha / inv-l

  const int tid  = threadIdx.x;
  const int lane = tid & 63;
  const int wave = tid >> 6;
  const int half = lane >> 5;
  const int l31  = lane & 31;

  // XCD-grouped decode: bx = ((b*16 + p*4 + c) << 3) | hk
  const int bx = blockIdx.x;
  const int hk = bx & 7;
  const int t6 = bx >> 3;
  const int b  = t6 >> 4;
  const int m6 = t6 & 15;
  const int p  = m6 >> 2;                // q-tile pair id: tiles (p, 7-p)
  const int h  = hk * 4 + (m6 & 3);

  // 1/sqrt(128) * log2(e): softmax runs in exp2 domain
  const float scale = 0.12751879523604785f;
  const int kvtile = (b * 8 + hk) * 16;  // ws tile-id base

  // DMA split: per wave 4 K-chunks then 4 V-chunks of 1 KB (T4 counting).
  auto dmaK = [&](int t_, char* dst) {
    const char* src = kvg + ((size_t)(kvtile + t_) << 15);
    #pragma unroll
    for (int i = 0; i < 4; ++i) {
      int c = wave * 4 + i;              // 16 K chunks over 4 waves
      __builtin_amdgcn_global_load_lds(
        (const __attribute__((address_space(1))) void*)(src + c * 1024 + lane * 16),
        (__attribute__((address_space(3))) void*)(dst + c * 1024),
        16, 0, 0);
    }
  };
  auto dmaV = [&](int t_, char* dst) {
    const char* src = kvg + ((size_t)(kvtile + t_) << 15) + 16384;
    #pragma unroll
    for (int i = 0; i < 4; ++i) {
      int c = wave * 4 + i;              // 16 V chunks over 4 waves
      __builtin_amdgcn_global_load_lds(
        (const __attribute__((address_space(1))) void*)(src + c * 1024 + lane * 16),
        (__attribute__((address_space(3))) void*)(dst + 16384 + c * 1024),
        16, 0, 0);
    }
  };

  dmaK(0, KV[0]);
  dmaV(0, KV[0]);
  int cur = 0;

  for (int ph = 0; ph < 2; ++ph) {
    const int qt = ph ? (7 - p) : p;
    const int wv = ph ? (3 - wave) : wave;   // reverse rows in phase B
    const int q0 = qt * BQ;
    const int wqb = q0 + wv * 32;
    const int qglob = wqb + l31;
    const int ntiles = 2 * (qt + 1);

    // Q fragments (read-once: nontemporal, keeps workspace L2-resident)
    v8bf qf[8];
    {
      const float* qp = qg + ((size_t)((b * NS + qglob) * NHQ + h)) * ND + half * 8;
      #pragma unroll
      for (int dM = 0; dM < 8; ++dM) {
        v4f f0 = __builtin_nontemporal_load((const v4f*)(qp + dM * 16));
        v4f f1 = __builtin_nontemporal_load((const v4f*)(qp + dM * 16 + 4));
        v8bf t;
        t[0]=(__bf16)(f0[0]*scale); t[1]=(__bf16)(f0[1]*scale);
        t[2]=(__bf16)(f0[2]*scale); t[3]=(__bf16)(f0[3]*scale);
        t[4]=(__bf16)(f1[0]*scale); t[5]=(__bf16)(f1[1]*scale);
        t[6]=(__bf16)(f1[2]*scale); t[7]=(__bf16)(f1[3]*scale);
        qf[dM] = t;
      }
    }

    v16f accO[4];
    #pragma unroll
    for (int dt = 0; dt < 4; ++dt)
      #pragma unroll
      for (int e = 0; e < 16; ++e) accO[dt][e] = 0.f;
    // static normalizer (R13): exact via rare fallback
    float m_run = 8.0f, l_run = 0.f;

    for (int t = 0; t < ntiles; ++t) {
      const int k0 = t * BK;
      const bool has_next = (t + 1 < ntiles) || (ph == 0);
      const int  tn = (t + 1 < ntiles) ? t + 1 : 0;
      const bool act = (k0 <= wqb + 31);
      const char* ksr = KV[cur];
      const char* vtr = KV[cur] + 16384;

      // K(t) landed (4 oldest); V(t) may still be in flight
      asm volatile("s_waitcnt vmcnt(4)" ::: "memory");
      __syncthreads();
      if (has_next) dmaK(tn, KV[cur ^ 1]);   // K(t+1) flies across barrier #2

      v16f s0, s1;
      if (act) {
        // --- S^T = K · Q^T: K A-frags inline (contiguous 1KB = lane*16) ---
        #pragma unroll
        for (int e = 0; e < 16; ++e) { s0[e] = 0.f; s1[e] = 0.f; }
        __builtin_amdgcn_s_setprio(1);
        #pragma unroll
        for (int dM = 0; dM < 8; ++dM) {
          v8bf ka = *(const v8bf*)(ksr + dM * 1024 + lane * 16);
          s0 = __builtin_amdgcn_mfma_f32_32x32x16_bf16(ka, qf[dM], s0, 0, 0, 0);
        }
        #pragma unroll
        for (int dM = 0; dM < 8; ++dM) {
          v8bf ka = *(const v8bf*)(ksr + (dM + 8) * 1024 + lane * 16);
          s1 = __builtin_amdgcn_mfma_f32_32x32x16_bf16(ka, qf[dM], s1, 0, 0, 0);
        }
        __builtin_amdgcn_s_setprio(0);
        // --- causal mask (diagonal region only) ---
        if (k0 + BK > wqb) {
          #pragma unroll
          for (int r = 0; r < 16; ++r) {
            int key = k0 + KOFF(r) + half * 8;
            if (key > qglob)      s0[r] = -INFINITY;
            if (key + 32 > qglob) s1[r] = -INFINITY;
          }
        }
        // --- exp with STATIC normalizer (no max/shfl on critical path) ---
        #pragma unroll
        for (int r = 0; r < 16; ++r) s0[r] = fexp2(s0[r] - m_run);
        #pragma unroll
        for (int r = 0; r < 16; ++r) s1[r] = fexp2(s1[r] - m_run);
      }

      // V(t) landed; K(t+1) (youngest 4) stays outstanding — never drain to 0
      if (has_next) { asm volatile("s_waitcnt vmcnt(4)" ::: "memory"); }
      else          { asm volatile("s_waitcnt vmcnt(0)" ::: "memory"); }
      __syncthreads();
      if (has_next) dmaV(tn, KV[cur ^ 1]);

      if (act) {
        // --- O += P V (A = P kappa-aligned, B = V image) ---
        __builtin_amdgcn_s_setprio(1);
        #pragma unroll
        for (int C = 0; C < 2; ++C) {
          #pragma unroll
          for (int cp = 0; cp < 2; ++cp) {
            v8bf pf;
            #pragma unroll
            for (int e = 0; e < 8; ++e)
              pf[e] = (__bf16)(C == 0 ? s0[cp * 8 + e] : s1[cp * 8 + e]);
            int g = (C * 2 + cp) * 2 + half;
            #pragma unroll
            for (int dt = 0; dt < 4; ++dt) {
              int d = dt * 32 + l31;
              v8bf vb = *(const v8bf*)(vtr + (d * 8 + (g ^ ((l31 >> 1) & 7))) * 16);
              accO[dt] = __builtin_amdgcn_mfma_f32_32x32x16_bf16(pf, vb, accO[dt], 0, 0, 0);
            }
          }
        }
        __builtin_amdgcn_s_setprio(0);
        // --- slack work: row sum + row max, rare exact renormalization ---
        float rs = 0.f, pm = 0.f;
        #pragma unroll
        for (int r = 0; r < 16; ++r) {
          rs += s0[r] + s1[r];
          pm = fmaxf(pm, fmaxf(s0[r], s1[r]));
        }
        rs += __shfl_xor(rs, 32);
        pm = fmaxf(pm, __shfl_xor(pm, 32));
        if (__builtin_expect(__any(pm > 256.f), 0)) {
          float al = pm > 256.f ? 1.f / pm : 1.f;
          if (half == 0) alq[wave * 32 + l31] = al;
          float4 alf[4];
          #pragma unroll
          for (int c = 0; c < 4; ++c)
            alf[c] = *(const float4*)(&alq[wave * 32 + 8 * c + 4 * half]);
          #pragma unroll
          for (int dt = 0; dt < 4; ++dt)
            #pragma unroll
            for (int r = 0; r < 16; ++r)
              accO[dt][r] *= ((const float*)&alf[r >> 2])[r & 3];
          l_run = (l_run + rs) * al;
          m_run += (pm > 256.f) ? flog2(pm) : 0.f;
        } else {
          l_run += rs;
        }
      }
      cur ^= 1;
    }

    // --- epilogue: O / l, nontemporal fp32 stores (write-once) ---
    if (half == 0) alq[wave * 32 + l31] = 1.f / l_run;
    float4 invf[4];
    #pragma unroll
    for (int c = 0; c < 4; ++c)
      invf[c] = *(const float4*)(&alq[wave * 32 + 8 * c + 4 * half]);
    #pragma unroll
    for (int dt = 0; dt < 4; ++dt) {
      #pragma unroll
      for (int r = 0; r < 16; ++r) {
        int qrow = (r & 3) + 8 * (r >> 2) + 4 * half;
        float* op = og + ((size_t)((b * NS + wqb + qrow) * NHQ + h)) * ND;
        __builtin_nontemporal_store(
            accO[dt][r] * ((const float*)&invf[r >> 2])[r & 3],
            op + dt * 32 + l31);
      }
    }
  }
}

extern "C" void kernel_launch(void* const* d_in, const int* in_sizes, int n_in,
                              void* d_out, int out_size, void* d_ws, size_t ws_size,
                              hipStream_t stream) {
  const float* q = (const float*)d_in[0];
  const float* k = (const float*)d_in[1];
  const float* v = (const float*)d_in[2];
  float* out = (float*)d_out;
  char* ws = (char*)d_ws;   // 16 MiB: 512 tiles x 32 KB (frag-ordered K | V)
  prep<<<dim3(4096 + 2048), 256, 0, stream>>>(k, v, ws);
  fattn<<<dim3(NB * NHQ * 4), 256, 0, stream>>>(q, ws, out);
}